// Round 3
// baseline (90.362 us; speedup 1.0000x reference)
//
#include <hip/hip_runtime.h>
#include <math.h>

// CropPoolLayer: TF crop_and_resize (bilinear, extrapolation=0) to 14x14
// fused with 2x2 max pool -> [N,7,7,C], NHWC fp32.
// bottom [B=2,H=64,W=64,C=512] fp32, rois [N,5] (bid,x1,y1,x2,y2), im_info[2].
//
// R3: block = (ROI, channel-half), 256 threads, 1 fp32 channel/thread.
// Single column sweep per ROI with rolling row window: each distinct
// (row,col) pixel loaded once per sweep (~140 loads/thread vs 420/ROI-lane
// before). y-lerp per column first (shared across 14 sample cols), then
// x-lerp per sample. All control/indices scalarized via readfirstlane so
// addressing is SALU + s-base loads. Requires sx,sy >= 0 (x2>=x1, y2>=y1).

constexpr int POOLSZ = 7;
constexpr int CROPSZ = 14;
constexpr int Hc = 64, Wc = 64, Cc = 512;

__device__ __forceinline__ int rfl(int x) { return __builtin_amdgcn_readfirstlane(x); }

__global__ __launch_bounds__(256, 3)
void crop_pool_kernel(const float* __restrict__ bottom,
                      const float* __restrict__ rois,
                      const float* __restrict__ im_info,
                      float* __restrict__ out, int nwg)
{
    // bijective XCD swizzle: keep (roi, half) pairs and neighbor ROIs on one XCD
    const int bid = blockIdx.x;
    const int q = nwg >> 3, r8 = nwg & 7;
    const int xcd = bid & 7, ii = bid >> 3;
    const int blk = (xcd < r8 ? xcd * (q + 1) : r8 * (q + 1) + (xcd - r8) * q) + ii;

    const int n    = blk >> 1;                  // ROI index
    const int half = blk & 1;                   // channel half
    const int ch   = half * 256 + threadIdx.x;  // 0..511

    const float im_h = im_info[0];
    const float im_w = im_info[1];
    const float* r5 = rois + n * 5;
    const int bb = rfl((int)r5[0]);
    const float rx1 = r5[1] / im_w;
    const float ry1 = r5[2] / im_h;
    const float rx2 = r5[3] / im_w;
    const float ry2 = r5[4] / im_h;

    // TF grid: coord = p1*(D-1) + i * ((p2-p1)*(D-1)/(CROP-1))
    const float sy = (ry2 - ry1) * (float)(Hc - 1) / (float)(CROPSZ - 1);
    const float sx = (rx2 - rx1) * (float)(Wc - 1) / (float)(CROPSZ - 1);
    const float oy = ry1 * (float)(Hc - 1);
    const float ox = rx1 * (float)(Wc - 1);

    // ---- y geometry (block-uniform; scalarized) ----
    int   y0s[CROPSZ];          // clamped floor rows (non-decreasing)
    int   vys[CROPSZ];          // validity
    float lys[CROPSZ];          // unclipped lerp weights (per reference)
#pragma unroll
    for (int i = 0; i < CROPSZ; ++i) {
        const float ys = fmaf((float)i, sy, oy);
        vys[i] = rfl((ys >= 0.0f && ys <= (float)(Hc - 1)) ? 1 : 0);
        const float fy = floorf(ys);
        lys[i] = ys - fy;
        y0s[i] = rfl((int)fminf(fmaxf(fy, 0.0f), (float)(Hc - 1)));
    }

    const float* __restrict__ bimg = bottom + (size_t)bb * (Hc * Wc * Cc);

    float pcv[CROPSZ], ncv[CROPSZ];             // prev/new column values (y-lerped)
    float acc[POOLSZ][POOLSZ];
#pragma unroll
    for (int a = 0; a < POOLSZ; ++a)
#pragma unroll
        for (int b = 0; b < POOLSZ; ++b) acc[a][b] = -INFINITY;

    // Load one pixel's channel: row/col scalar -> s-base + v-offset load.
    auto ldpix = [&](int row, int col) -> float {
        const float* p = bimg + ((size_t)row * Wc + col) * Cc;
        return p[ch];
    };

    // Advance column window to column cc: shift ncv->pcv, then rolling row
    // sweep loading each distinct row once; y-lerp into ncv (invalid rows -> 0).
    auto advcol = [&](int cc) {
#pragma unroll
        for (int i = 0; i < CROPSZ; ++i) pcv[i] = ncv[i];
        int rw = y0s[0];
        float pa = ldpix(rw, cc);
        float pb = ldpix(rw + 1 < Hc ? rw + 1 : Hc - 1, cc);
#pragma unroll
        for (int i = 0; i < CROPSZ; ++i) {
            while (rw < y0s[i]) {               // uniform scalar loop (steps of 1)
                ++rw;
                pa = pb;
                pb = ldpix(rw + 1 < Hc ? rw + 1 : Hc - 1, cc);
            }
            // y1==y0 cases have lys==0 so pb is harmlessly unused
            ncv[i] = vys[i] ? fmaf(pb - pa, lys[i], pa) : 0.0f;
        }
    };

    int ccur = rfl((int)fminf(fmaxf(floorf(ox), 0.0f), (float)(Wc - 1)));
#pragma unroll
    for (int i = 0; i < CROPSZ; ++i) ncv[i] = 0.0f;
    advcol(ccur);                               // window: ncv = col(ccur)

#pragma unroll
    for (int j = 0; j < CROPSZ; ++j) {
        const float xv = fmaf((float)j, sx, ox);
        const int   vx = rfl((xv >= 0.0f && xv <= (float)(Wc - 1)) ? 1 : 0);
        const float fx = floorf(xv);
        const float lx = xv - fx;               // unclipped, per reference
        const int   c0 = rfl((int)fminf(fmaxf(fx, 0.0f), (float)(Wc - 1)));
        const int  adv = rfl((lx != 0.0f && c0 < Wc - 1) ? 1 : 0);
        const int   pj = j >> 1;
        if (vx) {                               // uniform branch
            const int tj = c0 + adv;            // trigger column (monotone in j)
            while (ccur < tj) { ++ccur; advcol(ccur); }
            if (adv) {                          // pcv==col(c0), ncv==col(c0+1)
#pragma unroll
                for (int i = 0; i < CROPSZ; ++i) {
                    const float v = fmaf(ncv[i] - pcv[i], lx, pcv[i]);
                    acc[i >> 1][pj] = fmaxf(acc[i >> 1][pj], v);
                }
            } else {                            // lx==0: value is col(c0) exactly
#pragma unroll
                for (int i = 0; i < CROPSZ; ++i)
                    acc[i >> 1][pj] = fmaxf(acc[i >> 1][pj], ncv[i]);
            }
        } else {                                // masked sample -> max with 0
#pragma unroll
            for (int a = 0; a < POOLSZ; ++a)
                acc[a][pj] = fmaxf(acc[a][pj], 0.0f);
        }
    }

    // store: out[n][a][b][ch]
    float* __restrict__ obase = out + (size_t)n * (POOLSZ * POOLSZ) * Cc;
#pragma unroll
    for (int a = 0; a < POOLSZ; ++a)
#pragma unroll
        for (int b = 0; b < POOLSZ; ++b)
            obase[(size_t)(a * POOLSZ + b) * Cc + ch] = acc[a][b];
}

extern "C" void kernel_launch(void* const* d_in, const int* in_sizes, int n_in,
                              void* d_out, int out_size, void* d_ws, size_t ws_size,
                              hipStream_t stream) {
    const float* bottom  = (const float*)d_in[0];
    const float* rois    = (const float*)d_in[1];
    const float* im_info = (const float*)d_in[2];
    float* out = (float*)d_out;

    const int N = in_sizes[1] / 5;              // 512 ROIs
    const int nwg = 2 * N;                      // (ROI, channel-half) blocks

    crop_pool_kernel<<<nwg, 256, 0, stream>>>(bottom, rois, im_info, out, nwg);
}

// Round 4
// 38.025 us; speedup vs baseline: 2.3764x; 2.3764x over previous
//
#include <hip/hip_runtime.h>
#include <math.h>

// CropPoolLayer: TF crop_and_resize (bilinear, extrapolation=0) to 14x14
// fused with 2x2 max pool -> [N,7,7,C], NHWC fp32.
// bottom [B=2,H=64,W=64,C=512] fp32, rois [N,5] (bid,x1,y1,x2,y2), im_info[2].
//
// R4: back to per-cell blocks (R0's 70% occupancy / high MLP) + XCD swizzle
// (R1's proven FETCH lever) + cheaper arithmetic:
//  - weight-form bilinear (wtl,wtr,wbl,wbr per sample; 4 fma/component)
//  - scalar-uniform corner offsets (saddr + tid voffset, no per-load v-math)
//  - all 16 loads issued straight-line before arithmetic (max MLP)
//  - uniform all-valid fast path hoisted (always taken for this data)

constexpr int POOLSZ = 7;
constexpr int CROPSZ = 14;
constexpr int Hc = 64, Wc = 64, C4 = 128;     // C=512 -> 128 float4 lanes

__global__ __launch_bounds__(128)
void crop_pool_kernel(const float4* __restrict__ bot4,
                      const float* __restrict__ rois,
                      const float* __restrict__ im_info,
                      float4* __restrict__ out4, int nwg)
{
    // bijective XCD swizzle: nwg = N*49 is divisible by 8; contiguous logical
    // blocks (same ROI's 49 cells, neighboring ROIs) share one XCD's L2.
    const int bid = blockIdx.x;
    const int blk = (bid & 7) * (nwg >> 3) + (bid >> 3);

    const int n  = blk / (POOLSZ * POOLSZ);
    const int p  = blk - n * (POOLSZ * POOLSZ);
    const int py = p / POOLSZ;
    const int px = p - py * POOLSZ;

    const float im_h = im_info[0];
    const float im_w = im_info[1];
    const float* r5 = rois + n * 5;
    const int   bb  = (int)r5[0];
    const float rx1 = r5[1] / im_w;
    const float ry1 = r5[2] / im_h;
    const float rx2 = r5[3] / im_w;
    const float ry2 = r5[4] / im_h;

    // TF grid: coord = p1*(D-1) + i * ((p2-p1)*(D-1)/(CROP-1))
    const float sy = (ry2 - ry1) * (float)(Hc - 1) / (float)(CROPSZ - 1);
    const float sx = (rx2 - rx1) * (float)(Wc - 1) / (float)(CROPSZ - 1);
    const float oy = ry1 * (float)(Hc - 1);
    const float ox = rx1 * (float)(Wc - 1);

    int   rb0[2], rb1[2], xc0[2], xc1[2];      // row bases / col indices (uniform)
    float ly[2], lx[2];
    bool  vy[2], vx[2];
#pragma unroll
    for (int r = 0; r < 2; ++r) {
        const float ys = fmaf((float)(2 * py + r), sy, oy);
        vy[r] = (ys >= 0.0f) && (ys <= (float)(Hc - 1));
        const float fy = floorf(ys);
        ly[r] = ys - fy;                        // unclipped, per reference
        const int y0 = (int)fminf(fmaxf(fy, 0.0f), (float)(Hc - 1));
        const int y1 = (int)fminf(fmaxf(ceilf(ys), 0.0f), (float)(Hc - 1));
        rb0[r] = (bb * Hc + y0) * Wc;
        rb1[r] = (bb * Hc + y1) * Wc;

        const float xv = fmaf((float)(2 * px + r), sx, ox);
        vx[r] = (xv >= 0.0f) && (xv <= (float)(Wc - 1));
        const float fx = floorf(xv);
        lx[r] = xv - fx;
        xc0[r] = (int)fminf(fmaxf(fx, 0.0f), (float)(Wc - 1));
        xc1[r] = (int)fminf(fmaxf(ceilf(xv), 0.0f), (float)(Wc - 1));
    }

    const int tid = threadIdx.x;               // one float4 of channels

    // per-sample bilinear weights: v = wtl*tl + wtr*tr + wbl*bl + wbr*br
    float wtl[2][2], wtr[2][2], wbl[2][2], wbr[2][2];
#pragma unroll
    for (int r = 0; r < 2; ++r)
#pragma unroll
        for (int s = 0; s < 2; ++s) {
            const float myy = 1.0f - ly[r], mxx = 1.0f - lx[s];
            wtl[r][s] = myy * mxx;  wtr[r][s] = myy * lx[s];
            wbl[r][s] = ly[r] * mxx; wbr[r][s] = ly[r] * lx[s];
        }

    float4 acc;
    const bool allv = vy[0] && vy[1] && vx[0] && vx[1];   // uniform; ~always true

    if (allv) {
        // 16 independent loads, issued straight-line (scalar saddr + tid voffset)
        float4 t00tl = bot4[(rb0[0] + xc0[0]) * C4 + tid];
        float4 t00tr = bot4[(rb0[0] + xc1[0]) * C4 + tid];
        float4 t00bl = bot4[(rb1[0] + xc0[0]) * C4 + tid];
        float4 t00br = bot4[(rb1[0] + xc1[0]) * C4 + tid];
        float4 t01tl = bot4[(rb0[0] + xc0[1]) * C4 + tid];
        float4 t01tr = bot4[(rb0[0] + xc1[1]) * C4 + tid];
        float4 t01bl = bot4[(rb1[0] + xc0[1]) * C4 + tid];
        float4 t01br = bot4[(rb1[0] + xc1[1]) * C4 + tid];
        float4 t10tl = bot4[(rb0[1] + xc0[0]) * C4 + tid];
        float4 t10tr = bot4[(rb0[1] + xc1[0]) * C4 + tid];
        float4 t10bl = bot4[(rb1[1] + xc0[0]) * C4 + tid];
        float4 t10br = bot4[(rb1[1] + xc1[0]) * C4 + tid];
        float4 t11tl = bot4[(rb0[1] + xc0[1]) * C4 + tid];
        float4 t11tr = bot4[(rb0[1] + xc1[1]) * C4 + tid];
        float4 t11bl = bot4[(rb1[1] + xc0[1]) * C4 + tid];
        float4 t11br = bot4[(rb1[1] + xc1[1]) * C4 + tid];

#define BILIN(r, s, TL, TR, BL, BR, dst)                                     \
        {                                                                    \
            dst.x = fmaf(wbr[r][s], BR.x, fmaf(wbl[r][s], BL.x,              \
                    fmaf(wtr[r][s], TR.x, wtl[r][s] * TL.x)));               \
            dst.y = fmaf(wbr[r][s], BR.y, fmaf(wbl[r][s], BL.y,              \
                    fmaf(wtr[r][s], TR.y, wtl[r][s] * TL.y)));               \
            dst.z = fmaf(wbr[r][s], BR.z, fmaf(wbl[r][s], BL.z,              \
                    fmaf(wtr[r][s], TR.z, wtl[r][s] * TL.z)));               \
            dst.w = fmaf(wbr[r][s], BR.w, fmaf(wbl[r][s], BL.w,              \
                    fmaf(wtr[r][s], TR.w, wtl[r][s] * TL.w)));               \
        }

        float4 v00, v01, v10, v11;
        BILIN(0, 0, t00tl, t00tr, t00bl, t00br, v00);
        BILIN(0, 1, t01tl, t01tr, t01bl, t01br, v01);
        BILIN(1, 0, t10tl, t10tr, t10bl, t10br, v10);
        BILIN(1, 1, t11tl, t11tr, t11bl, t11br, v11);
#undef BILIN
        acc.x = fmaxf(fmaxf(v00.x, v01.x), fmaxf(v10.x, v11.x));
        acc.y = fmaxf(fmaxf(v00.y, v01.y), fmaxf(v10.y, v11.y));
        acc.z = fmaxf(fmaxf(v00.z, v01.z), fmaxf(v10.z, v11.z));
        acc.w = fmaxf(fmaxf(v00.w, v01.w), fmaxf(v10.w, v11.w));
    } else {
        // general path: per-sample validity, masked samples contribute 0
        acc = make_float4(-INFINITY, -INFINITY, -INFINITY, -INFINITY);
#pragma unroll
        for (int r = 0; r < 2; ++r)
#pragma unroll
            for (int s = 0; s < 2; ++s) {
                float4 v = make_float4(0.f, 0.f, 0.f, 0.f);
                if (vy[r] && vx[s]) {
                    const float4 tl = bot4[(rb0[r] + xc0[s]) * C4 + tid];
                    const float4 tr = bot4[(rb0[r] + xc1[s]) * C4 + tid];
                    const float4 bl = bot4[(rb1[r] + xc0[s]) * C4 + tid];
                    const float4 br = bot4[(rb1[r] + xc1[s]) * C4 + tid];
                    v.x = fmaf(wbr[r][s], br.x, fmaf(wbl[r][s], bl.x,
                          fmaf(wtr[r][s], tr.x, wtl[r][s] * tl.x)));
                    v.y = fmaf(wbr[r][s], br.y, fmaf(wbl[r][s], bl.y,
                          fmaf(wtr[r][s], tr.y, wtl[r][s] * tl.y)));
                    v.z = fmaf(wbr[r][s], br.z, fmaf(wbl[r][s], bl.z,
                          fmaf(wtr[r][s], tr.z, wtl[r][s] * tl.z)));
                    v.w = fmaf(wbr[r][s], br.w, fmaf(wbl[r][s], bl.w,
                          fmaf(wtr[r][s], tr.w, wtl[r][s] * tl.w)));
                }
                acc.x = fmaxf(acc.x, v.x); acc.y = fmaxf(acc.y, v.y);
                acc.z = fmaxf(acc.z, v.z); acc.w = fmaxf(acc.w, v.w);
            }
    }

    out4[(size_t)blk * C4 + tid] = acc;
}

extern "C" void kernel_launch(void* const* d_in, const int* in_sizes, int n_in,
                              void* d_out, int out_size, void* d_ws, size_t ws_size,
                              hipStream_t stream) {
    const float4* bottom  = (const float4*)d_in[0];
    const float*  rois    = (const float*)d_in[1];
    const float*  im_info = (const float*)d_in[2];
    float4* out = (float4*)d_out;

    const int N = in_sizes[1] / 5;             // 512 ROIs
    const int nwg = N * POOLSZ * POOLSZ;       // 25088, divisible by 8

    crop_pool_kernel<<<nwg, 128, 0, stream>>>(bottom, rois, im_info, out, nwg);
}

// Round 5
// 32.965 us; speedup vs baseline: 2.7411x; 1.1535x over previous
//
#include <hip/hip_runtime.h>
#include <math.h>

// CropPoolLayer: TF crop_and_resize (bilinear, extrapolation=0) to 14x14
// fused with 2x2 max pool -> [N,7,7,C], NHWC fp32.
// bottom [B=2,H=64,W=64,C=512] fp32, rois [N,5] (bid,x1,y1,x2,y2), im_info[2].
//
// R5: per-cell blocks (high occupancy/MLP) + XCD swizzle + UNIFORM-BRANCH
// corner dedup. With sx,sy ~0.15..1.2, a cell's 4 corner cols are typically
// ~2.7 distinct (same for rows) -> ~7 loads instead of 16. All geometry is
// lane-uniform per block, so `if (cB != cA) load else copy` compiles to an
// execz-skipped branch: skipped loads are never issued (saves L2-side BW).
// Two-stage lerp (x-lerp per distinct row slot, then y-lerp) matches the
// reference's exact arithmetic ordering and lets row-equal slots reuse
// already-lerped values.

constexpr int POOLSZ = 7;
constexpr int CROPSZ = 14;
constexpr int Hc = 64, Wc = 64, C4 = 128;     // C=512 -> 128 float4 lanes

__device__ __forceinline__ float4 lerp4(float4 a, float4 b, float t) {
    return make_float4(fmaf(b.x - a.x, t, a.x),
                       fmaf(b.y - a.y, t, a.y),
                       fmaf(b.z - a.z, t, a.z),
                       fmaf(b.w - a.w, t, a.w));
}
__device__ __forceinline__ float4 f4max(float4 a, float4 b) {
    return make_float4(fmaxf(a.x, b.x), fmaxf(a.y, b.y),
                       fmaxf(a.z, b.z), fmaxf(a.w, b.w));
}
__device__ __forceinline__ float4 mask4(float4 v, bool ok) {
    return ok ? v : make_float4(0.f, 0.f, 0.f, 0.f);
}

__global__ __launch_bounds__(128)
void crop_pool_kernel(const float4* __restrict__ bot4,
                      const float* __restrict__ rois,
                      const float* __restrict__ im_info,
                      float4* __restrict__ out4, int nwg)
{
    // bijective XCD swizzle (nwg divisible by 8): same-ROI cells share an XCD L2
    const int bid = blockIdx.x;
    const int blk = (bid & 7) * (nwg >> 3) + (bid >> 3);

    const int n  = blk / (POOLSZ * POOLSZ);
    const int p  = blk - n * (POOLSZ * POOLSZ);
    const int py = p / POOLSZ;
    const int px = p - py * POOLSZ;

    const float im_h = im_info[0], im_w = im_info[1];
    const float* r5 = rois + n * 5;
    const int bb = (int)r5[0];
    const float rx1 = r5[1] / im_w, ry1 = r5[2] / im_h;
    const float rx2 = r5[3] / im_w, ry2 = r5[4] / im_h;

    // TF grid: coord = p1*(D-1) + i * ((p2-p1)*(D-1)/(CROP-1))
    const float sy = (ry2 - ry1) * (float)(Hc - 1) / (float)(CROPSZ - 1);
    const float sx = (rx2 - rx1) * (float)(Wc - 1) / (float)(CROPSZ - 1);
    const float oy = ry1 * (float)(Hc - 1);
    const float ox = rx1 * (float)(Wc - 1);

    // ---- y geometry: 4 row slots (pre-multiplied to float4-element bases) ----
    int R0, R1, R2, R3;
    float ly0, ly1; bool vy0, vy1;
    {
        const float ysa = fmaf((float)(2 * py), sy, oy);
        vy0 = (ysa >= 0.f) && (ysa <= (float)(Hc - 1));
        const float fy = floorf(ysa); ly0 = ysa - fy;          // unclipped
        const int y0 = (int)fminf(fmaxf(fy, 0.f), (float)(Hc - 1));
        const int y1 = (int)fminf(fmaxf(ceilf(ysa), 0.f), (float)(Hc - 1));
        R0 = ((bb * Hc + y0) * Wc) * C4;
        R1 = ((bb * Hc + y1) * Wc) * C4;
        const float ysb = fmaf((float)(2 * py + 1), sy, oy);
        vy1 = (ysb >= 0.f) && (ysb <= (float)(Hc - 1));
        const float fy2 = floorf(ysb); ly1 = ysb - fy2;
        const int y2 = (int)fminf(fmaxf(fy2, 0.f), (float)(Hc - 1));
        const int y3 = (int)fminf(fmaxf(ceilf(ysb), 0.f), (float)(Hc - 1));
        R2 = ((bb * Hc + y2) * Wc) * C4;
        R3 = ((bb * Hc + y3) * Wc) * C4;
    }
    // ---- x geometry: 4 corner columns (pre-multiplied) ----
    int cA, cB, cC, cD;
    float lx0, lx1; bool vx0, vx1;
    {
        const float xsa = fmaf((float)(2 * px), sx, ox);
        vx0 = (xsa >= 0.f) && (xsa <= (float)(Wc - 1));
        const float fx = floorf(xsa); lx0 = xsa - fx;          // unclipped
        cA = (int)fminf(fmaxf(fx, 0.f), (float)(Wc - 1)) * C4;
        cB = (int)fminf(fmaxf(ceilf(xsa), 0.f), (float)(Wc - 1)) * C4;
        const float xsb = fmaf((float)(2 * px + 1), sx, ox);
        vx1 = (xsb >= 0.f) && (xsb <= (float)(Wc - 1));
        const float fx2 = floorf(xsb); lx1 = xsb - fx2;
        cC = (int)fminf(fmaxf(fx2, 0.f), (float)(Wc - 1)) * C4;
        cD = (int)fminf(fmaxf(ceilf(xsb), 0.f), (float)(Wc - 1)) * C4;
    }

    const int tid = threadIdx.x;                 // one float4 of channels

    // X[slot][s]: x-lerped value at row slot, sample column s (static names)
    float4 X00, X01, X10, X11, X20, X21, X30, X31;

    // Load + x-lerp one row slot with column dedup (uniform branches:
    // skipped loads are never issued). Copy semantics are bit-exact to the
    // reference (equal indices -> equal corner values -> identical lerp).
    auto fresh = [&](int rb, float4& Xs0, float4& Xs1) {
        const float4 a = bot4[rb + cA + tid];
        float4 b; if (cB != cA) b = bot4[rb + cB + tid]; else b = a;
        float4 c; if (cC == cA) c = a; else if (cC == cB) c = b;
                  else c = bot4[rb + cC + tid];
        float4 d; if (cD == cC) d = c; else if (cD == cB) d = b;
                  else d = bot4[rb + cD + tid];
        Xs0 = lerp4(a, b, lx0);
        Xs1 = lerp4(c, d, lx1);
    };

    fresh(R0, X00, X01);
    if (R1 == R0)      { X10 = X00; X11 = X01; }
    else                 fresh(R1, X10, X11);
    if (R2 == R0)      { X20 = X00; X21 = X01; }
    else if (R2 == R1) { X20 = X10; X21 = X11; }
    else                 fresh(R2, X20, X21);
    if (R3 == R2)      { X30 = X20; X31 = X21; }
    else if (R3 == R1) { X30 = X10; X31 = X11; }
    else                 fresh(R3, X30, X31);

    // y-lerp (reference order: top + (bot-top)*ly), mask invalid samples to 0
    const float4 v00 = lerp4(X00, X10, ly0);
    const float4 v01 = lerp4(X01, X11, ly0);
    const float4 v10 = lerp4(X20, X30, ly1);
    const float4 v11 = lerp4(X21, X31, ly1);

    const float4 acc = f4max(
        f4max(mask4(v00, vy0 && vx0), mask4(v01, vy0 && vx1)),
        f4max(mask4(v10, vy1 && vx0), mask4(v11, vy1 && vx1)));

    out4[(size_t)blk * C4 + tid] = acc;
}

extern "C" void kernel_launch(void* const* d_in, const int* in_sizes, int n_in,
                              void* d_out, int out_size, void* d_ws, size_t ws_size,
                              hipStream_t stream) {
    const float4* bottom  = (const float4*)d_in[0];
    const float*  rois    = (const float*)d_in[1];
    const float*  im_info = (const float*)d_in[2];
    float4* out = (float4*)d_out;

    const int N = in_sizes[1] / 5;               // 512 ROIs
    const int nwg = N * POOLSZ * POOLSZ;         // 25088, divisible by 8

    crop_pool_kernel<<<nwg, 128, 0, stream>>>(bottom, rois, im_info, out, nwg);
}

// Round 7
// 31.582 us; speedup vs baseline: 2.8612x; 1.0438x over previous
//
#include <hip/hip_runtime.h>
#include <math.h>

// CropPoolLayer: TF crop_and_resize (bilinear, extrapolation=0) to 14x14
// fused with 2x2 max pool -> [N,7,7,C], NHWC fp32.
// bottom [B=2,H=64,W=64,C=512] fp32, rois [N,5] (bid,x1,y1,x2,y2), im_info[2].
//
// R7 = R6 with the nontemporal store fixed: __builtin_nontemporal_store
// requires a NATIVE clang vector type, not HIP's float4 class -> use
// ext_vector_type(4). Rest unchanged:
//  - per-cell blocks + XCD swizzle + uniform-branch corner dedup
//  - readfirstlane'd premultiplied indices -> saddr loads, s_cmp branches
//  - reciprocal-mul ROI normalization (im=1024 pow2 -> bit-identical)
//  - nt output stores: 50 MB write-once stream doesn't evict input from L2

constexpr int POOLSZ = 7;
constexpr int CROPSZ = 14;
constexpr int Hc = 64, Wc = 64, C4 = 128;     // C=512 -> 128 float4 lanes

typedef float vfloat4 __attribute__((ext_vector_type(4)));

__device__ __forceinline__ float4 lerp4(float4 a, float4 b, float t) {
    return make_float4(fmaf(b.x - a.x, t, a.x),
                       fmaf(b.y - a.y, t, a.y),
                       fmaf(b.z - a.z, t, a.z),
                       fmaf(b.w - a.w, t, a.w));
}
__device__ __forceinline__ float4 f4max(float4 a, float4 b) {
    return make_float4(fmaxf(a.x, b.x), fmaxf(a.y, b.y),
                       fmaxf(a.z, b.z), fmaxf(a.w, b.w));
}
__device__ __forceinline__ float4 mask4(float4 v, bool ok) {
    return ok ? v : make_float4(0.f, 0.f, 0.f, 0.f);
}
__device__ __forceinline__ int rfl(int x) { return __builtin_amdgcn_readfirstlane(x); }

__global__ __launch_bounds__(128)
void crop_pool_kernel(const float4* __restrict__ bot4,
                      const float* __restrict__ rois,
                      const float* __restrict__ im_info,
                      float4* __restrict__ out4, int nwg)
{
    // bijective XCD swizzle (nwg divisible by 8): same-ROI cells share an XCD L2
    const int bid = blockIdx.x;
    const int blk = (bid & 7) * (nwg >> 3) + (bid >> 3);

    const int n  = blk / (POOLSZ * POOLSZ);
    const int p  = blk - n * (POOLSZ * POOLSZ);
    const int py = p / POOLSZ;
    const int px = p - py * POOLSZ;

    const float inv_w = 1.0f / im_info[1];     // im=1024 (pow2) -> exact
    const float inv_h = 1.0f / im_info[0];
    const float* r5 = rois + n * 5;
    const int bb = rfl((int)r5[0]);
    const float rx1 = r5[1] * inv_w, ry1 = r5[2] * inv_h;
    const float rx2 = r5[3] * inv_w, ry2 = r5[4] * inv_h;

    // TF grid: coord = p1*(D-1) + i * ((p2-p1)*(D-1)/(CROP-1))
    const float sy = (ry2 - ry1) * (float)(Hc - 1) / (float)(CROPSZ - 1);
    const float sx = (rx2 - rx1) * (float)(Wc - 1) / (float)(CROPSZ - 1);
    const float oy = ry1 * (float)(Hc - 1);
    const float ox = rx1 * (float)(Wc - 1);

    // ---- y geometry: 4 row slots (premultiplied, scalarized) ----
    int R0, R1, R2, R3;
    float ly0, ly1; bool vy0, vy1;
    {
        const float ysa = fmaf((float)(2 * py), sy, oy);
        vy0 = (ysa >= 0.f) && (ysa <= (float)(Hc - 1));
        const float fy = floorf(ysa); ly0 = ysa - fy;          // unclipped
        const int y0 = (int)fminf(fmaxf(fy, 0.f), (float)(Hc - 1));
        const int y1 = (int)fminf(fmaxf(ceilf(ysa), 0.f), (float)(Hc - 1));
        R0 = rfl(((bb * Hc + y0) * Wc) * C4);
        R1 = rfl(((bb * Hc + y1) * Wc) * C4);
        const float ysb = fmaf((float)(2 * py + 1), sy, oy);
        vy1 = (ysb >= 0.f) && (ysb <= (float)(Hc - 1));
        const float fy2 = floorf(ysb); ly1 = ysb - fy2;
        const int y2 = (int)fminf(fmaxf(fy2, 0.f), (float)(Hc - 1));
        const int y3 = (int)fminf(fmaxf(ceilf(ysb), 0.f), (float)(Hc - 1));
        R2 = rfl(((bb * Hc + y2) * Wc) * C4);
        R3 = rfl(((bb * Hc + y3) * Wc) * C4);
    }
    // ---- x geometry: 4 corner columns (premultiplied, scalarized) ----
    int cA, cB, cC, cD;
    float lx0, lx1; bool vx0, vx1;
    {
        const float xsa = fmaf((float)(2 * px), sx, ox);
        vx0 = (xsa >= 0.f) && (xsa <= (float)(Wc - 1));
        const float fx = floorf(xsa); lx0 = xsa - fx;          // unclipped
        cA = rfl((int)fminf(fmaxf(fx, 0.f), (float)(Wc - 1)) * C4);
        cB = rfl((int)fminf(fmaxf(ceilf(xsa), 0.f), (float)(Wc - 1)) * C4);
        const float xsb = fmaf((float)(2 * px + 1), sx, ox);
        vx1 = (xsb >= 0.f) && (xsb <= (float)(Wc - 1));
        const float fx2 = floorf(xsb); lx1 = xsb - fx2;
        cC = rfl((int)fminf(fmaxf(fx2, 0.f), (float)(Wc - 1)) * C4);
        cD = rfl((int)fminf(fmaxf(ceilf(xsb), 0.f), (float)(Wc - 1)) * C4);
    }

    const int tid = threadIdx.x;                 // one float4 of channels

    // X[slot][s]: x-lerped value at row slot, sample column s (static names)
    float4 X00, X01, X10, X11, X20, X21, X30, X31;

    // Load + x-lerp one row slot with column dedup. Indices are SGPRs, so the
    // branches are s_cmp/s_cbranch (no exec churn) and loads are saddr-form.
    // Copy semantics are bit-exact (equal indices -> identical lerp inputs).
    auto fresh = [&](int rb, float4& Xs0, float4& Xs1) {
        const float4 a = bot4[rb + cA + tid];
        float4 b; if (cB != cA) b = bot4[rb + cB + tid]; else b = a;
        float4 c; if (cC == cA) c = a; else if (cC == cB) c = b;
                  else c = bot4[rb + cC + tid];
        float4 d; if (cD == cC) d = c; else if (cD == cB) d = b;
                  else d = bot4[rb + cD + tid];
        Xs0 = lerp4(a, b, lx0);
        Xs1 = lerp4(c, d, lx1);
    };

    fresh(R0, X00, X01);
    if (R1 == R0)      { X10 = X00; X11 = X01; }
    else                 fresh(R1, X10, X11);
    if (R2 == R0)      { X20 = X00; X21 = X01; }
    else if (R2 == R1) { X20 = X10; X21 = X11; }
    else                 fresh(R2, X20, X21);
    if (R3 == R2)      { X30 = X20; X31 = X21; }
    else if (R3 == R1) { X30 = X10; X31 = X11; }
    else                 fresh(R3, X30, X31);

    // y-lerp (reference order: top + (bot-top)*ly), mask invalid samples to 0
    const float4 v00 = lerp4(X00, X10, ly0);
    const float4 v01 = lerp4(X01, X11, ly0);
    const float4 v10 = lerp4(X20, X30, ly1);
    const float4 v11 = lerp4(X21, X31, ly1);

    const float4 acc = f4max(
        f4max(mask4(v00, vy0 && vx0), mask4(v01, vy0 && vx1)),
        f4max(mask4(v10, vy1 && vx0), mask4(v11, vy1 && vx1)));

    // write-once output: nontemporal (native vector type required by builtin)
    vfloat4 accv; accv.x = acc.x; accv.y = acc.y; accv.z = acc.z; accv.w = acc.w;
    vfloat4* dst = reinterpret_cast<vfloat4*>(&out4[(size_t)blk * C4 + tid]);
    __builtin_nontemporal_store(accv, dst);
}

extern "C" void kernel_launch(void* const* d_in, const int* in_sizes, int n_in,
                              void* d_out, int out_size, void* d_ws, size_t ws_size,
                              hipStream_t stream) {
    const float4* bottom  = (const float4*)d_in[0];
    const float*  rois    = (const float*)d_in[1];
    const float*  im_info = (const float*)d_in[2];
    float4* out = (float4*)d_out;

    const int N = in_sizes[1] / 5;               // 512 ROIs
    const int nwg = N * POOLSZ * POOLSZ;         // 25088, divisible by 8

    crop_pool_kernel<<<nwg, 128, 0, stream>>>(bottom, rois, im_info, out, nwg);
}